// Round 1
// baseline (210.559 us; speedup 1.0000x reference)
//
#include <hip/hip_runtime.h>
#include <hip/hip_bf16.h>
#include <math.h>

constexpr int NCAPS = 1152;
constexpr int CIN   = 8;
constexpr int COUT  = 16;
constexpr int BATCH = 128;
constexpr int DCAPS = 10;

// Fully fused capsule-routing kernel.
// One block per (d, b); 256 threads = 4 waves; 1280 blocks = exactly 5
// blocks/CU in one occupancy pass (launch_bounds(256,5) caps VGPR at 102).
//
// Phase 1: each thread computes u[n, o-half] for its 9 n-rows directly from
// x and w (fp32 FMA, same order as the old u_kernel) and packs to bf16 in
// registers (upk, 36 VGPR) -- the exact register layout the old
// routing_kernel loaded from HBM. This deletes the 47 MB u write + 47 MB
// u read through HBM.
//
// Phase 2: identical 3-iteration routing, in-register.
//
// Block->(d,b) mapping groups same-d blocks onto the same XCD (assuming
// round-robin blockIdx->XCD dispatch): d 0..7 -> XCD d (128 blocks each),
// d 8/9 interleaved on even/odd XCDs. Each XCD's L2 then holds its
// 0.6-1.2 MB w slice, so w is fetched from HBM only once (5.9 MB total)
// and the 754 MB of per-block w streaming is served by L2.

constexpr int BNT  = 256;
constexpr int BWAV = BNT / 64;
constexpr int JPT  = 9;               // n-rows per thread: 1152*2/256

__device__ __forceinline__ void unpack8(const uint4 pv, float* f) {
    f[0] = __uint_as_float(pv.x << 16);
    f[1] = __uint_as_float(pv.x & 0xffff0000u);
    f[2] = __uint_as_float(pv.y << 16);
    f[3] = __uint_as_float(pv.y & 0xffff0000u);
    f[4] = __uint_as_float(pv.z << 16);
    f[5] = __uint_as_float(pv.z & 0xffff0000u);
    f[6] = __uint_as_float(pv.w << 16);
    f[7] = __uint_as_float(pv.w & 0xffff0000u);
}

__global__ __launch_bounds__(BNT, 5) void fused_caps_kernel(
    const float* __restrict__ x,      // [128, 1152, 8]
    const float* __restrict__ w,      // [10, 1152, 8, 16]
    float* __restrict__ out)          // [10, 128, 16]
{
    __shared__ float red[BWAV][COUT]; // per-wave partial s
    __shared__ float zred[BWAV];      // per-wave exp-sum
    __shared__ float vsh[COUT];       // squashed v

    // ---- block -> (d, b), XCD-grouped by d (bijective over 1280) ----
    const int i = blockIdx.x;
    int d, b;
    if (i < 1024) { d = i & 7; b = i >> 3; }
    else { const int j = i - 1024; d = 8 + (j & 1); b = j >> 1; }

    const int t    = threadIdx.x;
    const int wave = t >> 6;
    const int lane = t & 63;
    const int oh   = t & 1;           // o-half: 0 -> o 0..7, 1 -> o 8..15
    const int r    = t >> 1;          // 0..127

    // ---- Phase 1: compute u for this (d,b) into packed-bf16 registers ----
    const float* xb = x + (size_t)b * (NCAPS * CIN);
    const float* wd = w + (size_t)d * ((size_t)NCAPS * CIN * COUT) + oh * 8;

    uint4 upk[JPT];
    #pragma unroll
    for (int j = 0; j < JPT; ++j) {
        const int n = j * 128 + r;
        const float4* xr = (const float4*)(xb + (size_t)n * CIN);
        const float4 xa = xr[0], xc = xr[1];
        const float xs[CIN] = {xa.x, xa.y, xa.z, xa.w, xc.x, xc.y, xc.z, xc.w};
        const float* wr = wd + (size_t)n * (CIN * COUT);
        float4 a0 = {0.f, 0.f, 0.f, 0.f};
        float4 a1 = {0.f, 0.f, 0.f, 0.f};
        #pragma unroll
        for (int ii = 0; ii < CIN; ++ii) {
            const float4 w0 = *(const float4*)(wr + ii * COUT);
            const float4 w1 = *(const float4*)(wr + ii * COUT + 4);
            a0.x = fmaf(xs[ii], w0.x, a0.x);
            a0.y = fmaf(xs[ii], w0.y, a0.y);
            a0.z = fmaf(xs[ii], w0.z, a0.z);
            a0.w = fmaf(xs[ii], w0.w, a0.w);
            a1.x = fmaf(xs[ii], w1.x, a1.x);
            a1.y = fmaf(xs[ii], w1.y, a1.y);
            a1.z = fmaf(xs[ii], w1.z, a1.z);
            a1.w = fmaf(xs[ii], w1.w, a1.w);
        }
        union { unsigned short us[8]; uint4 v; } pk;
        pk.us[0] = __bfloat16_as_ushort(__float2bfloat16(a0.x));
        pk.us[1] = __bfloat16_as_ushort(__float2bfloat16(a0.y));
        pk.us[2] = __bfloat16_as_ushort(__float2bfloat16(a0.z));
        pk.us[3] = __bfloat16_as_ushort(__float2bfloat16(a0.w));
        pk.us[4] = __bfloat16_as_ushort(__float2bfloat16(a1.x));
        pk.us[5] = __bfloat16_as_ushort(__float2bfloat16(a1.y));
        pk.us[6] = __bfloat16_as_ushort(__float2bfloat16(a1.z));
        pk.us[7] = __bfloat16_as_ushort(__float2bfloat16(a1.w));
        upk[j] = pk.v;
    }

    // ---- Phase 2: 3-iteration routing, all in registers (unchanged) ----
    float bb[JPT];
    #pragma unroll
    for (int j = 0; j < JPT; ++j) bb[j] = 0.f;

    #pragma unroll
    for (int it = 0; it < 3; ++it) {
        float p8[8] = {0.f,0.f,0.f,0.f,0.f,0.f,0.f,0.f};
        float z = 0.f;
        if (it == 0) {
            #pragma unroll
            for (int j = 0; j < JPT; ++j) {
                float uf[8]; unpack8(upk[j], uf);
                #pragma unroll
                for (int k = 0; k < 8; ++k) p8[k] += uf[k];
            }
        } else {
            #pragma unroll
            for (int j = 0; j < JPT; ++j) {
                float e = __expf(bb[j] - 20.f);   // constant-shift softmax
                z += e;
                float uf[8]; unpack8(upk[j], uf);
                #pragma unroll
                for (int k = 0; k < 8; ++k) p8[k] = fmaf(e, uf[k], p8[k]);
            }
        }
        // reduce over the wave's 32 r-lanes (lane bits 1..5). After this,
        // lane 0 (oh=0) and lane 1 (oh=1) hold the wave sums for their o's;
        // z on lane {0,1} counts each n exactly once.
        #pragma unroll
        for (int off = 2; off < 64; off <<= 1) {
            #pragma unroll
            for (int k = 0; k < 8; ++k) p8[k] += __shfl_xor(p8[k], off);
            if (it != 0) z += __shfl_xor(z, off);
        }
        if (lane < 2) {
            #pragma unroll
            for (int k = 0; k < 8; ++k) red[wave][oh * 8 + k] = p8[k];
            if (it != 0 && lane == 0) zred[wave] = z;
        }
        __syncthreads();

        if (t < COUT) {   // t == o: combine waves, squash, publish
            float s = red[0][t];
            #pragma unroll
            for (int wv = 1; wv < BWAV; ++wv) s += red[wv][t];
            float scale;
            if (it == 0) {
                scale = 1.f / (float)NCAPS;
            } else {
                float Z = zred[0];
                #pragma unroll
                for (int wv = 1; wv < BWAV; ++wv) Z += zred[wv];
                scale = 1.f / Z;
            }
            s *= scale;
            float v = s * fabsf(s) / (1.f + s * s);
            vsh[t] = v;
            if (it == 2)
                out[((size_t)d * BATCH + b) * COUT + t] = v;
        }
        __syncthreads();

        if (it < 2) {
            float vloc[8];
            #pragma unroll
            for (int k = 0; k < 8; ++k) vloc[k] = vsh[oh * 8 + k];
            #pragma unroll
            for (int j = 0; j < JPT; ++j) {
                float uf[8]; unpack8(upk[j], uf);
                float dv = 0.f;
                #pragma unroll
                for (int k = 0; k < 8; ++k) dv = fmaf(uf[k], vloc[k], dv);
                dv += __shfl_xor(dv, 1);   // add the other o-half
                bb[j] += dv;
            }
            __syncthreads();   // vsh/red reused next iteration
        }
    }
}

extern "C" void kernel_launch(void* const* d_in, const int* in_sizes, int n_in,
                              void* d_out, int out_size, void* d_ws, size_t ws_size,
                              hipStream_t stream) {
    const float* x = (const float*)d_in[0];
    const float* w = (const float*)d_in[1];
    float* out = (float*)d_out;
    (void)d_ws; (void)ws_size;

    fused_caps_kernel<<<DCAPS * BATCH, BNT, 0, stream>>>(x, w, out);
}

// Round 3
// 153.164 us; speedup vs baseline: 1.3747x; 1.3747x over previous
//
#include <hip/hip_runtime.h>
#include <hip/hip_bf16.h>
#include <math.h>

constexpr int NCAPS = 1152;
constexpr int CIN   = 8;
constexpr int COUT  = 16;
constexpr int BATCH = 128;
constexpr int DCAPS = 10;

// Fully fused capsule-routing kernel.
// One block per (d, b); 256 threads = 4 waves.
//
// R1 lesson: __launch_bounds__(256,5) made the allocator snap its VGPR
// budget down (to the 64-reg occupancy quantum), spilling upk to scratch:
// VGPR_Count=48 with 128 MB fetch + 146 MB write of pure scratch traffic,
// 210 us. Fix: (256,4) -> 128-VGPR budget; live peak ~90-110 fits, no spill.
// 4 blocks/CU -> 1024 resident, 1.25 passes over 1280 blocks (tail is cheap
// for an L2-BW-bound kernel: total w traffic is pass-invariant).
// (R2 bench was an infra failure -- container acquisition -- resubmitting.)
//
// Phase 1: each thread computes u[n, o-half] for its 9 n-rows directly from
// x and w (fp32 FMA) and packs to bf16 in registers (upk, 36 VGPR) -- the
// exact register layout the old standalone routing_kernel loaded from HBM.
// Deletes the 47 MB u write + 47 MB u read through HBM.
//
// Phase 2: 3-iteration routing, all in registers.
//
// Block->(d,b) mapping groups same-d blocks onto the same XCD (round-robin
// blockIdx->XCD dispatch): d 0..7 -> XCD d, d 8/9 interleaved. Each XCD's
// 4 MB L2 holds its w slice, so w hits HBM once (5.9 MB) and the 754 MB of
// per-block w streaming is served from L2.

constexpr int BNT  = 256;
constexpr int BWAV = BNT / 64;
constexpr int JPT  = 9;               // n-rows per thread: 1152*2/256

__device__ __forceinline__ void unpack8(const uint4 pv, float* f) {
    f[0] = __uint_as_float(pv.x << 16);
    f[1] = __uint_as_float(pv.x & 0xffff0000u);
    f[2] = __uint_as_float(pv.y << 16);
    f[3] = __uint_as_float(pv.y & 0xffff0000u);
    f[4] = __uint_as_float(pv.z << 16);
    f[5] = __uint_as_float(pv.z & 0xffff0000u);
    f[6] = __uint_as_float(pv.w << 16);
    f[7] = __uint_as_float(pv.w & 0xffff0000u);
}

__global__ __launch_bounds__(BNT, 4) void fused_caps_kernel(
    const float* __restrict__ x,      // [128, 1152, 8]
    const float* __restrict__ w,      // [10, 1152, 8, 16]
    float* __restrict__ out)          // [10, 128, 16]
{
    __shared__ float red[BWAV][COUT]; // per-wave partial s
    __shared__ float zred[BWAV];      // per-wave exp-sum
    __shared__ float vsh[COUT];       // squashed v

    // ---- block -> (d, b), XCD-grouped by d (bijective over 1280) ----
    const int i = blockIdx.x;
    int d, b;
    if (i < 1024) { d = i & 7; b = i >> 3; }
    else { const int j = i - 1024; d = 8 + (j & 1); b = j >> 1; }

    const int t    = threadIdx.x;
    const int wave = t >> 6;
    const int lane = t & 63;
    const int oh   = t & 1;           // o-half: 0 -> o 0..7, 1 -> o 8..15
    const int r    = t >> 1;          // 0..127

    // ---- Phase 1: compute u for this (d,b) into packed-bf16 registers ----
    const float* xb = x + (size_t)b * (NCAPS * CIN);
    const float* wd = w + (size_t)d * ((size_t)NCAPS * CIN * COUT) + oh * 8;

    uint4 upk[JPT];
    #pragma unroll
    for (int j = 0; j < JPT; ++j) {
        const int n = j * 128 + r;
        const float4* xr = (const float4*)(xb + (size_t)n * CIN);
        const float4 xa = xr[0], xc = xr[1];
        const float xs[CIN] = {xa.x, xa.y, xa.z, xa.w, xc.x, xc.y, xc.z, xc.w};
        const float* wr = wd + (size_t)n * (CIN * COUT);
        float4 a0 = {0.f, 0.f, 0.f, 0.f};
        float4 a1 = {0.f, 0.f, 0.f, 0.f};
        #pragma unroll
        for (int ii = 0; ii < CIN; ++ii) {
            const float4 w0 = *(const float4*)(wr + ii * COUT);
            const float4 w1 = *(const float4*)(wr + ii * COUT + 4);
            a0.x = fmaf(xs[ii], w0.x, a0.x);
            a0.y = fmaf(xs[ii], w0.y, a0.y);
            a0.z = fmaf(xs[ii], w0.z, a0.z);
            a0.w = fmaf(xs[ii], w0.w, a0.w);
            a1.x = fmaf(xs[ii], w1.x, a1.x);
            a1.y = fmaf(xs[ii], w1.y, a1.y);
            a1.z = fmaf(xs[ii], w1.z, a1.z);
            a1.w = fmaf(xs[ii], w1.w, a1.w);
        }
        union { unsigned short us[8]; uint4 v; } pk;
        pk.us[0] = __bfloat16_as_ushort(__float2bfloat16(a0.x));
        pk.us[1] = __bfloat16_as_ushort(__float2bfloat16(a0.y));
        pk.us[2] = __bfloat16_as_ushort(__float2bfloat16(a0.z));
        pk.us[3] = __bfloat16_as_ushort(__float2bfloat16(a0.w));
        pk.us[4] = __bfloat16_as_ushort(__float2bfloat16(a1.x));
        pk.us[5] = __bfloat16_as_ushort(__float2bfloat16(a1.y));
        pk.us[6] = __bfloat16_as_ushort(__float2bfloat16(a1.z));
        pk.us[7] = __bfloat16_as_ushort(__float2bfloat16(a1.w));
        upk[j] = pk.v;
    }

    // ---- Phase 2: 3-iteration routing, all in registers ----
    float bb[JPT];
    #pragma unroll
    for (int j = 0; j < JPT; ++j) bb[j] = 0.f;

    #pragma unroll
    for (int it = 0; it < 3; ++it) {
        float p8[8] = {0.f,0.f,0.f,0.f,0.f,0.f,0.f,0.f};
        float z = 0.f;
        if (it == 0) {
            #pragma unroll
            for (int j = 0; j < JPT; ++j) {
                float uf[8]; unpack8(upk[j], uf);
                #pragma unroll
                for (int k = 0; k < 8; ++k) p8[k] += uf[k];
            }
        } else {
            #pragma unroll
            for (int j = 0; j < JPT; ++j) {
                float e = __expf(bb[j] - 20.f);   // constant-shift softmax
                z += e;
                float uf[8]; unpack8(upk[j], uf);
                #pragma unroll
                for (int k = 0; k < 8; ++k) p8[k] = fmaf(e, uf[k], p8[k]);
            }
        }
        // reduce over the wave's 32 r-lanes (lane bits 1..5). After this,
        // lane 0 (oh=0) and lane 1 (oh=1) hold the wave sums for their o's;
        // z on lane {0,1} counts each n exactly once.
        #pragma unroll
        for (int off = 2; off < 64; off <<= 1) {
            #pragma unroll
            for (int k = 0; k < 8; ++k) p8[k] += __shfl_xor(p8[k], off);
            if (it != 0) z += __shfl_xor(z, off);
        }
        if (lane < 2) {
            #pragma unroll
            for (int k = 0; k < 8; ++k) red[wave][oh * 8 + k] = p8[k];
            if (it != 0 && lane == 0) zred[wave] = z;
        }
        __syncthreads();

        if (t < COUT) {   // t == o: combine waves, squash, publish
            float s = red[0][t];
            #pragma unroll
            for (int wv = 1; wv < BWAV; ++wv) s += red[wv][t];
            float scale;
            if (it == 0) {
                scale = 1.f / (float)NCAPS;
            } else {
                float Z = zred[0];
                #pragma unroll
                for (int wv = 1; wv < BWAV; ++wv) Z += zred[wv];
                scale = 1.f / Z;
            }
            s *= scale;
            float v = s * fabsf(s) / (1.f + s * s);
            vsh[t] = v;
            if (it == 2)
                out[((size_t)d * BATCH + b) * COUT + t] = v;
        }
        __syncthreads();

        if (it < 2) {
            float vloc[8];
            #pragma unroll
            for (int k = 0; k < 8; ++k) vloc[k] = vsh[oh * 8 + k];
            #pragma unroll
            for (int j = 0; j < JPT; ++j) {
                float uf[8]; unpack8(upk[j], uf);
                float dv = 0.f;
                #pragma unroll
                for (int k = 0; k < 8; ++k) dv = fmaf(uf[k], vloc[k], dv);
                dv += __shfl_xor(dv, 1);   // add the other o-half
                bb[j] += dv;
            }
            __syncthreads();   // vsh/red reused next iteration
        }
    }
}

extern "C" void kernel_launch(void* const* d_in, const int* in_sizes, int n_in,
                              void* d_out, int out_size, void* d_ws, size_t ws_size,
                              hipStream_t stream) {
    const float* x = (const float*)d_in[0];
    const float* w = (const float*)d_in[1];
    float* out = (float*)d_out;
    (void)d_ws; (void)ws_size;

    fused_caps_kernel<<<DCAPS * BATCH, BNT, 0, stream>>>(x, w, out);
}

// Round 4
// 146.525 us; speedup vs baseline: 1.4370x; 1.0453x over previous
//
#include <hip/hip_runtime.h>
#include <hip/hip_bf16.h>
#include <math.h>

constexpr int NCAPS = 1152;
constexpr int CIN   = 8;
constexpr int COUT  = 16;
constexpr int BATCH = 128;
constexpr int DCAPS = 10;

// Fully fused capsule-routing kernel.
// One block per (d, b); 256 threads = 4 waves.
//
// R1/R3 lesson: __launch_bounds__' 2nd arg is only a MIN waves/EU. The
// AMDGPU occupancy heuristic kept targeting 8-10 waves/EU (VGPR 48/64),
// spilling upk to scratch: R3 showed WRITE_SIZE=38MB == one upk spill-store
// per thread (reads were L2-absorbed; FETCH=43MB is fully explained by
// per-XCD x refetch 8x4.7MB + w 5.9MB). Fix: amdgpu_waves_per_eu(4,4)
// pins BOTH min and max -> extra occupancy impossible -> allocator has no
// reason to shrink below the 128-VGPR budget -> upk (36 regs) stays in
// registers.
//
// Phase 1: each thread computes u[n, o-half] for its 9 n-rows directly from
// x and w (fp32 FMA) and packs to bf16 in registers (upk) -- the exact
// register layout the old standalone routing_kernel loaded from HBM.
// Deletes the 47 MB u write + 47 MB u read through HBM.
//
// Phase 2: 3-iteration routing, all in registers.
//
// Block->(d,b) mapping groups same-d blocks onto the same XCD (round-robin
// blockIdx->XCD dispatch): d 0..7 -> XCD d, d 8/9 interleaved. Each XCD's
// 4 MB L2 holds its w slice, so w hits HBM once (5.9 MB) and the 754 MB of
// per-block w streaming is served from L2.

constexpr int BNT  = 256;
constexpr int BWAV = BNT / 64;
constexpr int JPT  = 9;               // n-rows per thread: 1152*2/256

__device__ __forceinline__ void unpack8(const uint4 pv, float* f) {
    f[0] = __uint_as_float(pv.x << 16);
    f[1] = __uint_as_float(pv.x & 0xffff0000u);
    f[2] = __uint_as_float(pv.y << 16);
    f[3] = __uint_as_float(pv.y & 0xffff0000u);
    f[4] = __uint_as_float(pv.z << 16);
    f[5] = __uint_as_float(pv.z & 0xffff0000u);
    f[6] = __uint_as_float(pv.w << 16);
    f[7] = __uint_as_float(pv.w & 0xffff0000u);
}

__global__ __launch_bounds__(BNT)
__attribute__((amdgpu_waves_per_eu(4, 4)))
void fused_caps_kernel(
    const float* __restrict__ x,      // [128, 1152, 8]
    const float* __restrict__ w,      // [10, 1152, 8, 16]
    float* __restrict__ out)          // [10, 128, 16]
{
    __shared__ float red[BWAV][COUT]; // per-wave partial s
    __shared__ float zred[BWAV];      // per-wave exp-sum
    __shared__ float vsh[COUT];       // squashed v

    // ---- block -> (d, b), XCD-grouped by d (bijective over 1280) ----
    const int i = blockIdx.x;
    int d, b;
    if (i < 1024) { d = i & 7; b = i >> 3; }
    else { const int j = i - 1024; d = 8 + (j & 1); b = j >> 1; }

    const int t    = threadIdx.x;
    const int wave = t >> 6;
    const int lane = t & 63;
    const int oh   = t & 1;           // o-half: 0 -> o 0..7, 1 -> o 8..15
    const int r    = t >> 1;          // 0..127

    // ---- Phase 1: compute u for this (d,b) into packed-bf16 registers ----
    const float* xb = x + (size_t)b * (NCAPS * CIN);
    const float* wd = w + (size_t)d * ((size_t)NCAPS * CIN * COUT) + oh * 8;

    uint4 upk[JPT];
    #pragma unroll
    for (int j = 0; j < JPT; ++j) {
        const int n = j * 128 + r;
        const float4* xr = (const float4*)(xb + (size_t)n * CIN);
        const float4 xa = xr[0], xc = xr[1];
        const float xs[CIN] = {xa.x, xa.y, xa.z, xa.w, xc.x, xc.y, xc.z, xc.w};
        const float* wr = wd + (size_t)n * (CIN * COUT);
        float4 a0 = {0.f, 0.f, 0.f, 0.f};
        float4 a1 = {0.f, 0.f, 0.f, 0.f};
        #pragma unroll
        for (int ii = 0; ii < CIN; ++ii) {
            const float4 w0 = *(const float4*)(wr + ii * COUT);
            const float4 w1 = *(const float4*)(wr + ii * COUT + 4);
            a0.x = fmaf(xs[ii], w0.x, a0.x);
            a0.y = fmaf(xs[ii], w0.y, a0.y);
            a0.z = fmaf(xs[ii], w0.z, a0.z);
            a0.w = fmaf(xs[ii], w0.w, a0.w);
            a1.x = fmaf(xs[ii], w1.x, a1.x);
            a1.y = fmaf(xs[ii], w1.y, a1.y);
            a1.z = fmaf(xs[ii], w1.z, a1.z);
            a1.w = fmaf(xs[ii], w1.w, a1.w);
        }
        union { unsigned short us[8]; uint4 v; } pk;
        pk.us[0] = __bfloat16_as_ushort(__float2bfloat16(a0.x));
        pk.us[1] = __bfloat16_as_ushort(__float2bfloat16(a0.y));
        pk.us[2] = __bfloat16_as_ushort(__float2bfloat16(a0.z));
        pk.us[3] = __bfloat16_as_ushort(__float2bfloat16(a0.w));
        pk.us[4] = __bfloat16_as_ushort(__float2bfloat16(a1.x));
        pk.us[5] = __bfloat16_as_ushort(__float2bfloat16(a1.y));
        pk.us[6] = __bfloat16_as_ushort(__float2bfloat16(a1.z));
        pk.us[7] = __bfloat16_as_ushort(__float2bfloat16(a1.w));
        upk[j] = pk.v;
    }

    // ---- Phase 2: 3-iteration routing, all in registers ----
    float bb[JPT];
    #pragma unroll
    for (int j = 0; j < JPT; ++j) bb[j] = 0.f;

    #pragma unroll
    for (int it = 0; it < 3; ++it) {
        float p8[8] = {0.f,0.f,0.f,0.f,0.f,0.f,0.f,0.f};
        float z = 0.f;
        if (it == 0) {
            #pragma unroll
            for (int j = 0; j < JPT; ++j) {
                float uf[8]; unpack8(upk[j], uf);
                #pragma unroll
                for (int k = 0; k < 8; ++k) p8[k] += uf[k];
            }
        } else {
            #pragma unroll
            for (int j = 0; j < JPT; ++j) {
                float e = __expf(bb[j] - 20.f);   // constant-shift softmax
                z += e;
                float uf[8]; unpack8(upk[j], uf);
                #pragma unroll
                for (int k = 0; k < 8; ++k) p8[k] = fmaf(e, uf[k], p8[k]);
            }
        }
        // reduce over the wave's 32 r-lanes (lane bits 1..5). After this,
        // lane 0 (oh=0) and lane 1 (oh=1) hold the wave sums for their o's;
        // z on lane {0,1} counts each n exactly once.
        #pragma unroll
        for (int off = 2; off < 64; off <<= 1) {
            #pragma unroll
            for (int k = 0; k < 8; ++k) p8[k] += __shfl_xor(p8[k], off);
            if (it != 0) z += __shfl_xor(z, off);
        }
        if (lane < 2) {
            #pragma unroll
            for (int k = 0; k < 8; ++k) red[wave][oh * 8 + k] = p8[k];
            if (it != 0 && lane == 0) zred[wave] = z;
        }
        __syncthreads();

        if (t < COUT) {   // t == o: combine waves, squash, publish
            float s = red[0][t];
            #pragma unroll
            for (int wv = 1; wv < BWAV; ++wv) s += red[wv][t];
            float scale;
            if (it == 0) {
                scale = 1.f / (float)NCAPS;
            } else {
                float Z = zred[0];
                #pragma unroll
                for (int wv = 1; wv < BWAV; ++wv) Z += zred[wv];
                scale = 1.f / Z;
            }
            s *= scale;
            float v = s * fabsf(s) / (1.f + s * s);
            vsh[t] = v;
            if (it == 2)
                out[((size_t)d * BATCH + b) * COUT + t] = v;
        }
        __syncthreads();

        if (it < 2) {
            float vloc[8];
            #pragma unroll
            for (int k = 0; k < 8; ++k) vloc[k] = vsh[oh * 8 + k];
            #pragma unroll
            for (int j = 0; j < JPT; ++j) {
                float uf[8]; unpack8(upk[j], uf);
                float dv = 0.f;
                #pragma unroll
                for (int k = 0; k < 8; ++k) dv = fmaf(uf[k], vloc[k], dv);
                dv += __shfl_xor(dv, 1);   // add the other o-half
                bb[j] += dv;
            }
            __syncthreads();   // vsh/red reused next iteration
        }
    }
}

extern "C" void kernel_launch(void* const* d_in, const int* in_sizes, int n_in,
                              void* d_out, int out_size, void* d_ws, size_t ws_size,
                              hipStream_t stream) {
    const float* x = (const float*)d_in[0];
    const float* w = (const float*)d_in[1];
    float* out = (float*)d_out;
    (void)d_ws; (void)ws_size;

    fused_caps_kernel<<<DCAPS * BATCH, BNT, 0, stream>>>(x, w, out);
}

// Round 5
// 115.509 us; speedup vs baseline: 1.8229x; 1.2685x over previous
//
#include <hip/hip_runtime.h>
#include <hip/hip_bf16.h>
#include <math.h>

constexpr int NCAPS = 1152;
constexpr int CIN   = 8;
constexpr int COUT  = 16;
constexpr int BATCH = 128;
constexpr int DCAPS = 10;

// Fully fused capsule-routing kernel. One block per (d, b); 256 threads.
//
// R1-R4 lesson: the AMDGPU register allocator pins this kernel at 64 VGPRs
// (launch_bounds mins and waves_per_eu(4,4) both failed to move it) and
// spills the 36-reg packed-u array to scratch: 38-86 MB of scratch traffic
// at ~1.5 TB/s dominated runtime (98-210 us across attempts).
//
// Fix: stop fighting the allocator. Each thread only ever re-reads ITS OWN
// u values, so u goes to LDS as explicitly-managed scratch:
//   u_lds[j*256 + t]   ((j*128+r)*2+oh == j*256+t -- contiguous per wave,
//                       ds_*_b128 over 1024 contiguous bytes, conflict-free)
// 36.9 KB LDS/block -> 4 blocks/CU (same occupancy as the spilling version)
// but register demand drops to ~45 -> zero scratch by construction.
// LDS traffic: 5 u-passes x 9 x 16 B = 720 B/thread (~230 MB aggregate,
// ~3 us at 69 TB/s) vs 86+ MB of HBM-class scratch before.
//
// Phase 1: thread computes u[n, o-half] for its 9 n-rows from x and w
// (fp32 FMA), packs to bf16, stores to its LDS slots.
// Phase 2: 3-iteration routing; u re-read from LDS.
//
// Block->(d,b) mapping groups same-d blocks onto the same XCD (round-robin
// blockIdx->XCD dispatch): d 0..7 -> XCD d, d 8/9 interleaved. Each XCD's
// 4 MB L2 holds its 0.6 MB w slice, so w hits HBM once (5.9 MB) and the
// 754 MB of per-block w streaming is served from L2 (~22 us floor).

constexpr int BNT  = 256;
constexpr int BWAV = BNT / 64;
constexpr int JPT  = 9;               // n-rows per thread: 1152*2/256

__device__ __forceinline__ void unpack8(const uint4 pv, float* f) {
    f[0] = __uint_as_float(pv.x << 16);
    f[1] = __uint_as_float(pv.x & 0xffff0000u);
    f[2] = __uint_as_float(pv.y << 16);
    f[3] = __uint_as_float(pv.y & 0xffff0000u);
    f[4] = __uint_as_float(pv.z << 16);
    f[5] = __uint_as_float(pv.z & 0xffff0000u);
    f[6] = __uint_as_float(pv.w << 16);
    f[7] = __uint_as_float(pv.w & 0xffff0000u);
}

__global__ __launch_bounds__(BNT) void fused_caps_kernel(
    const float* __restrict__ x,      // [128, 1152, 8]
    const float* __restrict__ w,      // [10, 1152, 8, 16]
    float* __restrict__ out)          // [10, 128, 16]
{
    __shared__ uint4  u_lds[JPT * BNT];   // 36864 B: packed bf16 u, per-thread slots
    __shared__ float  red[BWAV][COUT];    // per-wave partial s
    __shared__ float  zred[BWAV];         // per-wave exp-sum
    __shared__ float  vsh[COUT];          // squashed v

    // ---- block -> (d, b), XCD-grouped by d (bijective over 1280) ----
    const int i = blockIdx.x;
    int d, b;
    if (i < 1024) { d = i & 7; b = i >> 3; }
    else { const int j = i - 1024; d = 8 + (j & 1); b = j >> 1; }

    const int t    = threadIdx.x;
    const int wave = t >> 6;
    const int lane = t & 63;
    const int oh   = t & 1;           // o-half: 0 -> o 0..7, 1 -> o 8..15
    const int r    = t >> 1;          // 0..127

    // ---- Phase 1: compute u for this (d,b) into LDS (packed bf16) ----
    const float* xb = x + (size_t)b * (NCAPS * CIN);
    const float* wd = w + (size_t)d * ((size_t)NCAPS * CIN * COUT) + oh * 8;

    #pragma unroll
    for (int j = 0; j < JPT; ++j) {
        const int n = j * 128 + r;
        const float4* xr = (const float4*)(xb + (size_t)n * CIN);
        const float4 xa = xr[0], xc = xr[1];
        const float xs[CIN] = {xa.x, xa.y, xa.z, xa.w, xc.x, xc.y, xc.z, xc.w};
        const float* wr = wd + (size_t)n * (CIN * COUT);
        float4 a0 = {0.f, 0.f, 0.f, 0.f};
        float4 a1 = {0.f, 0.f, 0.f, 0.f};
        #pragma unroll
        for (int ii = 0; ii < CIN; ++ii) {
            const float4 w0 = *(const float4*)(wr + ii * COUT);
            const float4 w1 = *(const float4*)(wr + ii * COUT + 4);
            a0.x = fmaf(xs[ii], w0.x, a0.x);
            a0.y = fmaf(xs[ii], w0.y, a0.y);
            a0.z = fmaf(xs[ii], w0.z, a0.z);
            a0.w = fmaf(xs[ii], w0.w, a0.w);
            a1.x = fmaf(xs[ii], w1.x, a1.x);
            a1.y = fmaf(xs[ii], w1.y, a1.y);
            a1.z = fmaf(xs[ii], w1.z, a1.z);
            a1.w = fmaf(xs[ii], w1.w, a1.w);
        }
        union { unsigned short us[8]; uint4 v; } pk;
        pk.us[0] = __bfloat16_as_ushort(__float2bfloat16(a0.x));
        pk.us[1] = __bfloat16_as_ushort(__float2bfloat16(a0.y));
        pk.us[2] = __bfloat16_as_ushort(__float2bfloat16(a0.z));
        pk.us[3] = __bfloat16_as_ushort(__float2bfloat16(a0.w));
        pk.us[4] = __bfloat16_as_ushort(__float2bfloat16(a1.x));
        pk.us[5] = __bfloat16_as_ushort(__float2bfloat16(a1.y));
        pk.us[6] = __bfloat16_as_ushort(__float2bfloat16(a1.z));
        pk.us[7] = __bfloat16_as_ushort(__float2bfloat16(a1.w));
        u_lds[j * BNT + t] = pk.v;    // private slot; no cross-thread reads
    }

    // ---- Phase 2: 3-iteration routing; u re-read from LDS ----
    float bb[JPT];
    #pragma unroll
    for (int j = 0; j < JPT; ++j) bb[j] = 0.f;

    #pragma unroll
    for (int it = 0; it < 3; ++it) {
        float p8[8] = {0.f,0.f,0.f,0.f,0.f,0.f,0.f,0.f};
        float z = 0.f;
        if (it == 0) {
            #pragma unroll
            for (int j = 0; j < JPT; ++j) {
                float uf[8]; unpack8(u_lds[j * BNT + t], uf);
                #pragma unroll
                for (int k = 0; k < 8; ++k) p8[k] += uf[k];
            }
        } else {
            #pragma unroll
            for (int j = 0; j < JPT; ++j) {
                float e = __expf(bb[j] - 20.f);   // constant-shift softmax
                z += e;
                float uf[8]; unpack8(u_lds[j * BNT + t], uf);
                #pragma unroll
                for (int k = 0; k < 8; ++k) p8[k] = fmaf(e, uf[k], p8[k]);
            }
        }
        // reduce over the wave's 32 r-lanes (lane bits 1..5). After this,
        // lane 0 (oh=0) and lane 1 (oh=1) hold the wave sums for their o's;
        // z on lane {0,1} counts each n exactly once.
        #pragma unroll
        for (int off = 2; off < 64; off <<= 1) {
            #pragma unroll
            for (int k = 0; k < 8; ++k) p8[k] += __shfl_xor(p8[k], off);
            if (it != 0) z += __shfl_xor(z, off);
        }
        if (lane < 2) {
            #pragma unroll
            for (int k = 0; k < 8; ++k) red[wave][oh * 8 + k] = p8[k];
            if (it != 0 && lane == 0) zred[wave] = z;
        }
        __syncthreads();

        if (t < COUT) {   // t == o: combine waves, squash, publish
            float s = red[0][t];
            #pragma unroll
            for (int wv = 1; wv < BWAV; ++wv) s += red[wv][t];
            float scale;
            if (it == 0) {
                scale = 1.f / (float)NCAPS;
            } else {
                float Z = zred[0];
                #pragma unroll
                for (int wv = 1; wv < BWAV; ++wv) Z += zred[wv];
                scale = 1.f / Z;
            }
            s *= scale;
            float v = s * fabsf(s) / (1.f + s * s);
            vsh[t] = v;
            if (it == 2)
                out[((size_t)d * BATCH + b) * COUT + t] = v;
        }
        __syncthreads();

        if (it < 2) {
            float vloc[8];
            #pragma unroll
            for (int k = 0; k < 8; ++k) vloc[k] = vsh[oh * 8 + k];
            #pragma unroll
            for (int j = 0; j < JPT; ++j) {
                float uf[8]; unpack8(u_lds[j * BNT + t], uf);
                float dv = 0.f;
                #pragma unroll
                for (int k = 0; k < 8; ++k) dv = fmaf(uf[k], vloc[k], dv);
                dv += __shfl_xor(dv, 1);   // add the other o-half
                bb[j] += dv;
            }
            __syncthreads();   // vsh/red reused next iteration
        }
    }
}

extern "C" void kernel_launch(void* const* d_in, const int* in_sizes, int n_in,
                              void* d_out, int out_size, void* d_ws, size_t ws_size,
                              hipStream_t stream) {
    const float* x = (const float*)d_in[0];
    const float* w = (const float*)d_in[1];
    float* out = (float*)d_out;
    (void)d_ws; (void)ws_size;

    fused_caps_kernel<<<DCAPS * BATCH, BNT, 0, stream>>>(x, w, out);
}